// Round 3
// baseline (119.946 us; speedup 1.0000x reference)
//
#include <hip/hip_runtime.h>
#include <math.h>

#define NB 8192
#define NF 512
#define NP 64
#define NC 100
#define EPSF 1e-4f
#define LOG2E 1.44269504088896340736f

// Fully fused: per block = 8 rows of x. Phases:
//  A) GEMM: dots d(row, p) for all 64 p, K chunked by 64, w staged transposed
//     [k][p] in LDS (row stride 66 -> conflict-free b64 reads), software-
//     pipelined w prefetch; x read straight from global (L1 broadcast).
//  B) xsq / wsq partials (global re-read, L1-hot), fixed-order combines.
//  C) si = alpha*exp2(kgam*d), half-wave max, normalize -> si_lds.
//  D) u = beta^2 / sum(beta^2) into upad (union with w staging, stride 132).
//  E) 63-step Dempster scan (factored bilinear form, renorm every 4 steps),
//     final normalize, write out.
// All reductions fixed-order (graph-replay tripwire needs bitwise determinism).
__global__ __launch_bounds__(256, 4)
void ds_fused(const float* __restrict__ x, const float* __restrict__ w,
              const float* __restrict__ xi, const float* __restrict__ eta,
              const float* __restrict__ beta, float* __restrict__ out)
{
  // ---- LDS ----
  __shared__ __align__(16) float uni[64 * 132];  // wchT[64][66] (front) U upad[64][132]
  __shared__ __align__(16) float si_lds[8 * 64]; // xqp scratch first, then si
  __shared__ float wqp[256];                     // generic 256-float scratch
  __shared__ float wsql[64];                     // wsq, later binv
  __shared__ float xsql[8];
  float* wchT = uni;                              // [k][66], k in 0..63 (chunk-local)
  float* upad = uni;                              // [p][132], cols 100..131 zero

  const int t  = threadIdx.x;
  const int h  = t & 31;          // p-pair index: p = 2h, 2h+1
  const int rg = t >> 5;          // row 0..7
  const int R0 = blockIdx.x * 8;
  const float* xrow = x + (size_t)(R0 + rg) * NF;

  // ---- A) GEMM ----
  float dot0 = 0.f, dot1 = 0.f;
  float4 wpf[4];
  #pragma unroll
  for (int j = 0; j < 4; ++j) {
    const int f = t + 256 * j;                  // 0..1023
    const int p = f >> 4, kq = f & 15;
    wpf[j] = *(const float4*)&w[(size_t)p * NF + kq * 4];
  }
  for (int ch = 0; ch < 8; ++ch) {
    const int kc = ch * 64;
    __syncthreads();                            // prev chunk fully consumed
    #pragma unroll
    for (int j = 0; j < 4; ++j) {
      const int f = t + 256 * j;
      const int p = f >> 4, kq = f & 15;
      wchT[(kq*4+0)*66 + p] = wpf[j].x;
      wchT[(kq*4+1)*66 + p] = wpf[j].y;
      wchT[(kq*4+2)*66 + p] = wpf[j].z;
      wchT[(kq*4+3)*66 + p] = wpf[j].w;
    }
    __syncthreads();
    if (ch < 7) {                               // prefetch next chunk's w
      #pragma unroll
      for (int j = 0; j < 4; ++j) {
        const int f = t + 256 * j;
        const int p = f >> 4, kq = f & 15;
        wpf[j] = *(const float4*)&w[(size_t)p * NF + (kc + 64) + kq * 4];
      }
    }
    #pragma unroll 4
    for (int kq = 0; kq < 16; ++kq) {
      float4 xv = *(const float4*)&xrow[kc + kq * 4];
      float2 w0 = *(const float2*)&wchT[(kq*4+0)*66 + 2*h];
      float2 w1 = *(const float2*)&wchT[(kq*4+1)*66 + 2*h];
      float2 w2 = *(const float2*)&wchT[(kq*4+2)*66 + 2*h];
      float2 w3 = *(const float2*)&wchT[(kq*4+3)*66 + 2*h];
      dot0 = fmaf(xv.x, w0.x, dot0); dot1 = fmaf(xv.x, w0.y, dot1);
      dot0 = fmaf(xv.y, w1.x, dot0); dot1 = fmaf(xv.y, w1.y, dot1);
      dot0 = fmaf(xv.z, w2.x, dot0); dot1 = fmaf(xv.z, w2.y, dot1);
      dot0 = fmaf(xv.w, w3.x, dot0); dot1 = fmaf(xv.w, w3.y, dot1);
    }
  }

  // ---- B) xsq / wsq partials (L1-hot re-reads), fixed-order combine ----
  {
    const int rw = t >> 5, sl = t & 31;         // row rw, 16-k slice sl
    const float* xr = x + (size_t)(R0 + rw) * NF + sl * 16;
    float s = 0.f;
    #pragma unroll
    for (int j = 0; j < 4; ++j) {
      float4 v = *(const float4*)&xr[j * 4];
      s += v.x*v.x + v.y*v.y + v.z*v.z + v.w*v.w;
    }
    si_lds[t] = s;                              // xqp scratch in si region
  }
  {
    const int p = t & 63, hf = t >> 6;          // 128-k slice per p
    const float* wr = w + (size_t)p * NF + hf * 128;
    float s = 0.f;
    #pragma unroll 8
    for (int j = 0; j < 32; ++j) {
      float4 v = *(const float4*)&wr[j * 4];
      s += v.x*v.x + v.y*v.y + v.z*v.z + v.w*v.w;
    }
    wqp[hf * 64 + p] = s;
  }
  __syncthreads();
  if (t < 8) {
    float s = 0.f;
    #pragma unroll
    for (int i = 0; i < 32; ++i) s += si_lds[t * 32 + i];
    xsql[t] = s;
  }
  if (t < 64) wsql[t] = ((wqp[t] + wqp[64 + t]) + wqp[128 + t]) + wqp[192 + t];
  __syncthreads();

  // ---- C) si ----
  {
    const float xs = xsql[rg];
    const float d0 = xs + wsql[2*h]   - 2.f * dot0;
    const float d1 = xs + wsql[2*h+1] - 2.f * dot1;
    const float e0 = eta[2*h], e1 = eta[2*h+1];
    const float g0 = -LOG2E * e0 * e0, g1 = -LOG2E * e1 * e1;
    const float a0 = 1.f / (1.f + __expf(-xi[2*h]));
    const float a1 = 1.f / (1.f + __expf(-xi[2*h+1]));
    float si0 = a0 * exp2f(g0 * d0);
    float si1 = a1 * exp2f(g1 * d1);
    float mx = fmaxf(si0, si1);
    #pragma unroll
    for (int msk = 1; msk < 32; msk <<= 1) mx = fmaxf(mx, __shfl_xor(mx, msk, 64));
    const float rinv = 1.f / (mx + EPSF);
    *(float2*)&si_lds[rg * 64 + 2*h] = make_float2(si0 * rinv, si1 * rinv);
  }

  // ---- D) u into upad (union region; wchT is dead) ----
  {
    const int p4 = t >> 2, q4 = t & 3;
    const float* br = beta + p4 * NC + q4 * 25;
    float s = 0.f;
    #pragma unroll 5
    for (int j = 0; j < 25; ++j) { float b = br[j]; s = fmaf(b, b, s); }
    wqp[q4 * 64 + p4] = s;
  }
  __syncthreads();
  if (t < 64) wsql[t] = 1.f / (((wqp[t] + wqp[64 + t]) + wqp[128 + t]) + wqp[192 + t]);
  __syncthreads();
  {
    const int p4 = t >> 2, q4 = t & 3;
    const float bi = wsql[p4];
    #pragma unroll
    for (int i = 0; i < 8; ++i) {
      const int q = q4 + 4 * i;                 // col quad 0..31
      float4 uv = make_float4(0.f, 0.f, 0.f, 0.f);
      if (q < 25) {
        const float* br = beta + p4 * NC + q * 4;
        float b0 = br[0], b1 = br[1], b2 = br[2], b3 = br[3];
        uv = make_float4(b0*b0*bi, b1*b1*bi, b2*b2*bi, b3*b3*bi);
      }
      *(float4*)&upad[p4 * 132 + q * 4] = uv;
    }
  }
  __syncthreads();

  // ---- E) Dempster scan ----
  const bool isom = (h == 25);                  // class 100 = omega: lane 25 slot 0
  float4 u0 = *(const float4*)&upad[h * 4];
  float sp  = si_lds[rg * 64];
  float m0 = sp * u0.x, m1 = sp * u0.y, m2 = sp * u0.z, m3 = sp * u0.w;
  float om1 = 1.f - sp;
  if (isom) m0 = om1;

  for (int p = 1; p < NP; ++p) {
    sp = si_lds[rg * 64 + p];
    float4 u = *(const float4*)&upad[p * 132 + h * 4];
    float om2 = 1.f - sp;
    float nom = -(om1 * om2);
    float t20 = fmaf(sp, u.x, om2);
    t20 = isom ? (om2 + om2) : t20;             // omega slot: m2+om2 = 2*om2
    float t21 = fmaf(sp, u.y, om2);
    float t22 = fmaf(sp, u.z, om2);
    float t23 = fmaf(sp, u.w, om2);
    m0 = fmaf(m0 + om1, t20, nom);
    m1 = fmaf(m1 + om1, t21, nom);
    m2 = fmaf(m2 + om1, t22, nom);
    m3 = fmaf(m3 + om1, t23, nom);
    om1 = fmaf(nom, -2.f, -nom);                // 3*om1*om2
    if (isom) m0 = om1;
    if ((p & 3) == 0) {                         // pure-scale renorm (range control)
      float ss = (m0 + m1) + (m2 + m3);
      #pragma unroll
      for (int msk = 1; msk < 32; msk <<= 1) ss += __shfl_xor(ss, msk, 64);
      float rn = __builtin_amdgcn_rcpf(ss);
      m0 *= rn; m1 *= rn; m2 *= rn; m3 *= rn; om1 *= rn;
    }
  }

  float ss = (m0 + m1) + (m2 + m3);
  #pragma unroll
  for (int msk = 1; msk < 32; msk <<= 1) ss += __shfl_xor(ss, msk, 64);
  float rn = 1.f / ss;                          // final normalize (no EPS, per ref)
  m0 *= rn; m1 *= rn; m2 *= rn; m3 *= rn;

  float* orow = &out[(size_t)(R0 + rg) * 101];
  if (h < 25) {
    orow[h*4+0] = m0; orow[h*4+1] = m1;
    orow[h*4+2] = m2; orow[h*4+3] = m3;
  } else if (h == 25) {
    orow[100] = m0;
  }
}

extern "C" void kernel_launch(void* const* d_in, const int* in_sizes, int n_in,
                              void* d_out, int out_size, void* d_ws, size_t ws_size,
                              hipStream_t stream)
{
  const float* x    = (const float*)d_in[0];
  const float* w    = (const float*)d_in[1];
  const float* xi   = (const float*)d_in[2];
  const float* eta  = (const float*)d_in[3];
  const float* beta = (const float*)d_in[4];
  (void)d_ws; (void)ws_size;
  hipLaunchKernelGGL(ds_fused, dim3(1024), dim3(256), 0, stream,
                     x, w, xi, eta, beta, (float*)d_out);
}

// Round 4
// 98.298 us; speedup vs baseline: 1.2202x; 1.2202x over previous
//
#include <hip/hip_runtime.h>
#include <math.h>

#define NB 8192
#define NF 512
#define NP 64
#define NC 100
#define NSP 8                    // K-split factor
#define EPSF 1e-4f
#define LOG2E 1.44269504088896340736f

// ---- workspace layout (bytes) ----
// dpre: [8][NB][NP] f32 partial dots   = 16 MiB
// xsqp: [8][NB]     f32 partial ||x||^2 = 256 KiB
// upad: [NP][128]   f32 u (cols 100..127 zero) = 32 KiB
// wsq/kgam/alph: [NP] f32 each
#define DPRE_OFF   0ull
#define DPRE_SZ    ((size_t)NSP*NB*NP*4ull)
#define XSQP_OFF   (DPRE_OFF + DPRE_SZ)
#define XSQP_SZ    ((size_t)NSP*NB*4ull)
#define UPAD_OFF   (XSQP_OFF + XSQP_SZ)
#define UPAD_SZ    (NP*128ull*4ull)
#define WSQ_OFF    (UPAD_OFF + UPAD_SZ)
#define KGAM_OFF   (WSQ_OFF + 256ull)
#define ALPH_OFF   (KGAM_OFF + 256ull)

// K1: 1024 GEMM blocks: tile 64 rows x 64 p x 64 k (K-split 8 via blk&7),
// per-thread 4x4 accumulator, all-b128 LDS traffic (2 B/FMA — the per-CU
// LDS pipe is the wall; R3's 1r x 2p tile was 4 B/FMA and LDS-bound 2x over
// VALU). Block 1024 = parallel prep (wsq, kgam, alpha, upad).
// No atomics anywhere: graph-replay tripwire needs bitwise determinism.
__global__ __launch_bounds__(256, 4)
void ds_k1(const float* __restrict__ x, const float* __restrict__ w,
           const float* __restrict__ xi, const float* __restrict__ eta,
           const float* __restrict__ beta,
           float* __restrict__ dpre, float* __restrict__ xsqp,
           float* __restrict__ upad, float* __restrict__ wsq,
           float* __restrict__ kgam, float* __restrict__ alph)
{
  __shared__ __align__(16) float xt[64][68];   // stride 68: b128-aligned, 2-addr/bank-quad reads
  __shared__ __align__(16) float wtT[64][68];  // transposed [k][p], stride 68: 2-way-free reads
  __shared__ float sqp[64][17];                // per-(row, k-quad) |x|^2 partials
  const int blk = blockIdx.x;
  const int t   = threadIdx.x;

  if (blk == 1024) {            // ---- prep block (parallel, hidden under GEMM) ----
    __shared__ float red[256];
    {                           // wsq: 4 threads per p, 128-k slices
      const int p = t & 63, q = t >> 6;
      const float* wr = w + (size_t)p * NF + q * 128;
      float s = 0.f;
      #pragma unroll 8
      for (int j = 0; j < 32; ++j) {
        float4 v = *(const float4*)&wr[j * 4];
        s += v.x*v.x + v.y*v.y + v.z*v.z + v.w*v.w;
      }
      red[q * 64 + p] = s;
    }
    __syncthreads();
    if (t < 64) {
      wsq[t] = ((red[t] + red[64 + t]) + red[128 + t]) + red[192 + t];
      float e = eta[t];
      kgam[t] = -LOG2E * e * e;              // exp(-g*d) = exp2(kgam*d)
      alph[t] = 1.f / (1.f + __expf(-xi[t]));
    }
    __syncthreads();
    {                           // beta sumsq: 4 threads per p, 25-col slices
      const int p4 = t >> 2, q4 = t & 3;
      const float* br = beta + p4 * NC + q4 * 25;
      float s = 0.f;
      #pragma unroll 5
      for (int j = 0; j < 25; ++j) { float b = br[j]; s = fmaf(b, b, s); }
      red[q4 * 64 + p4] = s;
    }
    __syncthreads();
    __shared__ float binv[64];
    if (t < 64) binv[t] = 1.f / (((red[t] + red[64 + t]) + red[128 + t]) + red[192 + t]);
    __syncthreads();
    {                           // upad[p][128], cols 100..127 zero
      const int p4 = t >> 2, q4 = t & 3;
      const float bi = binv[p4];
      #pragma unroll
      for (int i = 0; i < 8; ++i) {
        const int q = q4 + 4 * i;            // col quad 0..31
        float4 uv = make_float4(0.f, 0.f, 0.f, 0.f);
        if (q < 25) {
          const float* br = beta + p4 * NC + q * 4;
          float b0 = br[0], b1 = br[1], b2 = br[2], b3 = br[3];
          uv = make_float4(b0*b0*bi, b1*b1*bi, b2*b2*bi, b3*b3*bi);
        }
        *(float4*)&upad[p4 * 128 + q * 4] = uv;
      }
    }
    return;
  }

  // ---- GEMM partial: rows [R0,R0+64) x 64 p x k in [kb,kb+64) ----
  const int s  = blk & 7;
  const int R0 = (blk >> 3) * 64;
  const int kb = s * 64;

  #pragma unroll
  for (int j = 0; j < 4; ++j) {              // single-shot staging, coalesced
    const int f   = t + 256 * j;             // 0..1023
    const int row = f >> 4;                  // 0..63 (== p for w)
    const int kq  = f & 15;
    float4 v = *(const float4*)&x[(size_t)(R0 + row) * NF + kb + kq * 4];
    *(float4*)&xt[row][kq * 4] = v;
    sqp[row][kq] = v.x*v.x + v.y*v.y + v.z*v.z + v.w*v.w;
    float4 wv = *(const float4*)&w[(size_t)row * NF + kb + kq * 4];
    wtT[kq*4+0][row] = wv.x; wtT[kq*4+1][row] = wv.y;
    wtT[kq*4+2][row] = wv.z; wtT[kq*4+3][row] = wv.w;
  }
  __syncthreads();

  float xacc = 0.f;
  if (t < 64) {                              // fixed-order, deterministic
    #pragma unroll
    for (int q = 0; q < 16; ++q) xacc += sqp[t][q];
  }

  const int r0 = (t >> 4) * 4;
  const int p0 = (t & 15) * 4;
  float acc[4][4] = {{0.f}};

  #pragma unroll 4
  for (int kq = 0; kq < 16; ++kq) {          // 8 b128 reads per 64 FMA
    float4 xv0 = *(const float4*)&xt[r0+0][kq*4];
    float4 xv1 = *(const float4*)&xt[r0+1][kq*4];
    float4 xv2 = *(const float4*)&xt[r0+2][kq*4];
    float4 xv3 = *(const float4*)&xt[r0+3][kq*4];
    float4 wv0 = *(const float4*)&wtT[kq*4+0][p0];  // (w[p0..p0+3][k+c]) in wvc
    float4 wv1 = *(const float4*)&wtT[kq*4+1][p0];
    float4 wv2 = *(const float4*)&wtT[kq*4+2][p0];
    float4 wv3 = *(const float4*)&wtT[kq*4+3][p0];
    #define ROWFMA(i, xv) \
      acc[i][0] = fmaf(xv.x, wv0.x, acc[i][0]); acc[i][1] = fmaf(xv.x, wv0.y, acc[i][1]); \
      acc[i][2] = fmaf(xv.x, wv0.z, acc[i][2]); acc[i][3] = fmaf(xv.x, wv0.w, acc[i][3]); \
      acc[i][0] = fmaf(xv.y, wv1.x, acc[i][0]); acc[i][1] = fmaf(xv.y, wv1.y, acc[i][1]); \
      acc[i][2] = fmaf(xv.y, wv1.z, acc[i][2]); acc[i][3] = fmaf(xv.y, wv1.w, acc[i][3]); \
      acc[i][0] = fmaf(xv.z, wv2.x, acc[i][0]); acc[i][1] = fmaf(xv.z, wv2.y, acc[i][1]); \
      acc[i][2] = fmaf(xv.z, wv2.z, acc[i][2]); acc[i][3] = fmaf(xv.z, wv2.w, acc[i][3]); \
      acc[i][0] = fmaf(xv.w, wv3.x, acc[i][0]); acc[i][1] = fmaf(xv.w, wv3.y, acc[i][1]); \
      acc[i][2] = fmaf(xv.w, wv3.z, acc[i][2]); acc[i][3] = fmaf(xv.w, wv3.w, acc[i][3]);
    ROWFMA(0, xv0) ROWFMA(1, xv1) ROWFMA(2, xv2) ROWFMA(3, xv3)
    #undef ROWFMA
  }

  #pragma unroll
  for (int i = 0; i < 4; ++i) {
    float4 st = make_float4(acc[i][0], acc[i][1], acc[i][2], acc[i][3]);
    *(float4*)&dpre[((size_t)s * NB + R0 + r0 + i) * NP + p0] = st;
  }
  if (t < 64) xsqp[(size_t)s * NB + R0 + t] = xacc;
}

// K2: per block 8 rows; half-wave (32 lanes) per row, 4 contiguous classes/lane.
// Preamble combines the 8 K-split partials, computes si (exp2, rowmax-norm),
// then 63 sequential Dempster steps with the factored bilinear form
//   c = (m1+om1)*(m2+om2) - om1*om2   (gives 3*om1*om2 at the omega slot),
// renormalizing every 4 steps (pure scale -> cancelled by final normalize).
__global__ __launch_bounds__(256, 4)
void ds_k2(const float* __restrict__ dpre, const float* __restrict__ xsqp,
           const float* __restrict__ upad, const float* __restrict__ wsq,
           const float* __restrict__ kgam, const float* __restrict__ alph,
           float* __restrict__ out)
{
  __shared__ __align__(16) float u_lds[NP * 128];
  __shared__ float si_lds[8][64];
  const int t = threadIdx.x;

  #pragma unroll
  for (int uu = 0; uu < 8; ++uu) {
    const int idx = (t + 256 * uu) * 4;
    *(float4*)&u_lds[idx] = *(const float4*)&upad[idx];
  }

  const int r    = t >> 5;          // local row 0..7 (half-wave per row)
  const int lane = t & 31;
  const int grow = blockIdx.x * 8 + r;
  const int p2   = lane * 2;

  float dot0 = 0.f, dot1 = 0.f, xs = 0.f;
  #pragma unroll
  for (int s = 0; s < NSP; ++s) {
    float2 v = *(const float2*)&dpre[((size_t)s * NB + grow) * NP + p2];
    dot0 += v.x; dot1 += v.y;
    xs   += xsqp[(size_t)s * NB + grow];
  }
  float d0  = xs + wsq[p2]   - 2.f * dot0;
  float d1  = xs + wsq[p2+1] - 2.f * dot1;
  float si0 = alph[p2]   * exp2f(kgam[p2]   * d0);
  float si1 = alph[p2+1] * exp2f(kgam[p2+1] * d1);
  float mx  = fmaxf(si0, si1);
  #pragma unroll
  for (int msk = 1; msk < 32; msk <<= 1) mx = fmaxf(mx, __shfl_xor(mx, msk, 64));
  float rinv = 1.f / (mx + EPSF);
  *(float2*)&si_lds[r][p2] = make_float2(si0 * rinv, si1 * rinv);
  __syncthreads();

  const bool isom = (lane == 25);   // class 100 (omega) lives at lane 25, slot 0
  float4 u0 = *(const float4*)&u_lds[lane * 4];
  float sp  = si_lds[r][0];
  float m0 = sp * u0.x, m1 = sp * u0.y, m2 = sp * u0.z, m3 = sp * u0.w;
  float om1 = 1.f - sp;
  if (isom) m0 = om1;

  for (int p = 1; p < NP; ++p) {
    sp = si_lds[r][p];
    float4 u = *(const float4*)&u_lds[p * 128 + lane * 4];
    float om2 = 1.f - sp;
    float nom = -(om1 * om2);
    float t20 = fmaf(sp, u.x, om2);
    t20 = isom ? (om2 + om2) : t20;        // omega slot: m2+om2 = 2*om2
    float t21 = fmaf(sp, u.y, om2);
    float t22 = fmaf(sp, u.z, om2);
    float t23 = fmaf(sp, u.w, om2);
    m0 = fmaf(m0 + om1, t20, nom);
    m1 = fmaf(m1 + om1, t21, nom);
    m2 = fmaf(m2 + om1, t22, nom);
    m3 = fmaf(m3 + om1, t23, nom);
    om1 = fmaf(nom, -2.f, -nom);           // 3*om1*om2
    if (isom) m0 = om1;                    // keep omega slot exactly consistent
    if ((p & 3) == 0) {                    // pure-scale renorm (range control)
      float ss = (m0 + m1) + (m2 + m3);
      #pragma unroll
      for (int msk = 1; msk < 32; msk <<= 1) ss += __shfl_xor(ss, msk, 64);
      float rn = __builtin_amdgcn_rcpf(ss);
      m0 *= rn; m1 *= rn; m2 *= rn; m3 *= rn; om1 *= rn;
    }
  }

  float ss = (m0 + m1) + (m2 + m3);
  #pragma unroll
  for (int msk = 1; msk < 32; msk <<= 1) ss += __shfl_xor(ss, msk, 64);
  float rn = 1.f / ss;                     // final normalize (no EPS, per ref)
  m0 *= rn; m1 *= rn; m2 *= rn; m3 *= rn;

  float* orow = &out[(size_t)grow * 101];
  if (lane < 25) {
    orow[lane*4+0] = m0; orow[lane*4+1] = m1;
    orow[lane*4+2] = m2; orow[lane*4+3] = m3;
  } else if (lane == 25) {
    orow[100] = m0;
  }
}

extern "C" void kernel_launch(void* const* d_in, const int* in_sizes, int n_in,
                              void* d_out, int out_size, void* d_ws, size_t ws_size,
                              hipStream_t stream)
{
  const float* x    = (const float*)d_in[0];
  const float* w    = (const float*)d_in[1];
  const float* xi   = (const float*)d_in[2];
  const float* eta  = (const float*)d_in[3];
  const float* beta = (const float*)d_in[4];
  char* ws = (char*)d_ws;
  float* dpre = (float*)(ws + DPRE_OFF);
  float* xsqp = (float*)(ws + XSQP_OFF);
  float* upad = (float*)(ws + UPAD_OFF);
  float* wsqp = (float*)(ws + WSQ_OFF);
  float* kgam = (float*)(ws + KGAM_OFF);
  float* alph = (float*)(ws + ALPH_OFF);

  hipLaunchKernelGGL(ds_k1, dim3(1025), dim3(256), 0, stream,
                     x, w, xi, eta, beta, dpre, xsqp, upad, wsqp, kgam, alph);
  hipLaunchKernelGGL(ds_k2, dim3(1024), dim3(256), 0, stream,
                     dpre, xsqp, upad, wsqp, kgam, alph, (float*)d_out);
}

// Round 6
// 95.656 us; speedup vs baseline: 1.2539x; 1.0276x over previous
//
#include <hip/hip_runtime.h>
#include <math.h>

#define NB 8192
#define NF 512
#define NP 64
#define NC 100
#define NR 16                     // rows per block
#define EPSF 1e-4f
#define LOG2E 1.44269504088896340736f

using short8  = __attribute__((ext_vector_type(8))) short;   // 8 bf16
using floatx4 = __attribute__((ext_vector_type(4))) float;   // MFMA acc

// split f32 -> bf16 hi (x) + bf16 lo (y); truncation split, residual ~2^-16
__device__ __forceinline__ short2 bsplit(float v) {
  unsigned b = __float_as_uint(v);
  short h = (short)(b >> 16);
  float hf = __uint_as_float(b & 0xFFFF0000u);
  float lo = v - hf;
  short l = (short)(__float_as_uint(lo) >> 16);
  return make_short2(h, l);
}

// Fully fused Dempster-Shafer forward.
// GEMM: D = x . w^T via 3 split-bf16 MFMAs (hi*hi + hi*lo + lo*hi), fp32 acc.
//   Missing lo*lo term: |dd| ~ 1e-3 -> si rel err <= 0.7% -> out err ~1e-4
//   (R2/R4 showed ~0.05x damping si->out; threshold is 2e-2).
// Scan: R4-verified half-wave/row kernel, 2 passes of 8 rows.
// All reductions fixed-order, no atomics (graph-replay bitwise determinism).
__global__ __launch_bounds__(256, 2)
void ds_fused2(const float* __restrict__ x, const float* __restrict__ w,
               const float* __restrict__ xi, const float* __restrict__ eta,
               const float* __restrict__ beta, float* __restrict__ out)
{
  // ---- LDS ----
  __shared__ __align__(16) short xhi_l[NR * 136];        // chunk 128k + pad, stride 136
  __shared__ __align__(16) short xlo_l[NR * 136];
  __shared__ __align__(16) char  wu_l[64 * 136 * 2 * 2]; // w_hi,w_lo (bf16) U u (f32, 64x128)
  __shared__ __align__(16) float d_l[NR * 68];
  __shared__ __align__(16) float si_l[NR * 64];
  __shared__ float sqp_l[NR * 17];
  __shared__ float red_l[256];
  __shared__ float xsql[NR];
  __shared__ float wsql[64], alph_l[64], kgam_l[64], binv_l[64];
  short* whi_l = (short*)wu_l;
  short* wlo_l = (short*)(wu_l + 64 * 136 * 2);
  float* u_l   = (float*)wu_l;                           // [p][128], cols 100..127 zero

  const int t  = threadIdx.x;
  const int R0 = blockIdx.x * NR;

  // staging roles
  const int xr_row = t >> 4, xr_sl = t & 15;             // x: 8 elems
  const int wr_p   = t >> 2, wr_q  = t & 3;              // w: 32 elems
  // MFMA roles
  const int wv = t >> 6;                                 // wave -> p-tile [16wv,16wv+16)
  const int ml = t & 15;                                 // m (A) / n (B) index
  const int qd = (t & 63) >> 4;                          // quad

  float xsq_acc = 0.f, wsq_acc = 0.f;
  floatx4 acc0 = {0.f, 0.f, 0.f, 0.f};
  floatx4 acc1 = {0.f, 0.f, 0.f, 0.f};

  for (int ch = 0; ch < 4; ++ch) {
    const int kb = ch * 128;
    __syncthreads();                                     // prev chunk consumed
    {                                                    // stage x (16x128)
      const float* xr = x + (size_t)(R0 + xr_row) * NF + kb + xr_sl * 8;
      float4 a = *(const float4*)&xr[0];
      float4 b = *(const float4*)&xr[4];
      xsq_acc += a.x*a.x + a.y*a.y + a.z*a.z + a.w*a.w
               + b.x*b.x + b.y*b.y + b.z*b.z + b.w*b.w;
      short8 hv, lv;
      short2 s0 = bsplit(a.x), s1 = bsplit(a.y), s2 = bsplit(a.z), s3 = bsplit(a.w);
      short2 s4 = bsplit(b.x), s5 = bsplit(b.y), s6 = bsplit(b.z), s7 = bsplit(b.w);
      hv[0]=s0.x; hv[1]=s1.x; hv[2]=s2.x; hv[3]=s3.x;
      hv[4]=s4.x; hv[5]=s5.x; hv[6]=s6.x; hv[7]=s7.x;
      lv[0]=s0.y; lv[1]=s1.y; lv[2]=s2.y; lv[3]=s3.y;
      lv[4]=s4.y; lv[5]=s5.y; lv[6]=s6.y; lv[7]=s7.y;
      *(short8*)&xhi_l[xr_row * 136 + xr_sl * 8] = hv;
      *(short8*)&xlo_l[xr_row * 136 + xr_sl * 8] = lv;
    }
    {                                                    // stage w (64x128)
      const float* wr = w + (size_t)wr_p * NF + kb + wr_q * 32;
      #pragma unroll
      for (int g = 0; g < 4; ++g) {
        float4 a = *(const float4*)&wr[g * 8];
        float4 b = *(const float4*)&wr[g * 8 + 4];
        wsq_acc += a.x*a.x + a.y*a.y + a.z*a.z + a.w*a.w
                 + b.x*b.x + b.y*b.y + b.z*b.z + b.w*b.w;
        short8 hv, lv;
        short2 s0 = bsplit(a.x), s1 = bsplit(a.y), s2 = bsplit(a.z), s3 = bsplit(a.w);
        short2 s4 = bsplit(b.x), s5 = bsplit(b.y), s6 = bsplit(b.z), s7 = bsplit(b.w);
        hv[0]=s0.x; hv[1]=s1.x; hv[2]=s2.x; hv[3]=s3.x;
        hv[4]=s4.x; hv[5]=s5.x; hv[6]=s6.x; hv[7]=s7.x;
        lv[0]=s0.y; lv[1]=s1.y; lv[2]=s2.y; lv[3]=s3.y;
        lv[4]=s4.y; lv[5]=s5.y; lv[6]=s6.y; lv[7]=s7.y;
        *(short8*)&whi_l[wr_p * 136 + wr_q * 32 + g * 8] = hv;
        *(short8*)&wlo_l[wr_p * 136 + wr_q * 32 + g * 8] = lv;
      }
    }
    __syncthreads();
    #pragma unroll
    for (int ks = 0; ks < 4; ++ks) {                     // 4 k-steps of 32
      short8 ah = *(const short8*)&xhi_l[ml * 136 + ks * 32 + qd * 8];
      short8 al = *(const short8*)&xlo_l[ml * 136 + ks * 32 + qd * 8];
      short8 bh = *(const short8*)&whi_l[(wv * 16 + ml) * 136 + ks * 32 + qd * 8];
      short8 bl = *(const short8*)&wlo_l[(wv * 16 + ml) * 136 + ks * 32 + qd * 8];
      acc0 = __builtin_amdgcn_mfma_f32_16x16x32_bf16(ah, bh, acc0, 0, 0, 0);
      acc1 = __builtin_amdgcn_mfma_f32_16x16x32_bf16(ah, bl, acc1, 0, 0, 0);
      acc1 = __builtin_amdgcn_mfma_f32_16x16x32_bf16(al, bh, acc1, 0, 0, 0);
    }
  }

  // ---- epilogue: D -> d_l; xsq/wsq partials ----
  {
    // C/D layout (m89/m91): col = lane&15 (= n = p-within-tile),
    //                       row = (lane>>4)*4 + reg (= m = x-row)
    #pragma unroll
    for (int i = 0; i < 4; ++i) {
      const int row = qd * 4 + i;
      d_l[row * 68 + wv * 16 + ml] = acc0[i] + acc1[i];
    }
    sqp_l[xr_row * 17 + xr_sl] = xsq_acc;
    red_l[wr_q * 64 + wr_p]    = wsq_acc;
  }
  __syncthreads();                                       // B1
  if (t < NR) {
    float s = 0.f;
    #pragma unroll
    for (int q = 0; q < 16; ++q) s += sqp_l[t * 17 + q];
    xsql[t] = s;
  }
  if (t < 64) {
    wsql[t] = ((red_l[t] + red_l[64 + t]) + red_l[128 + t]) + red_l[192 + t];
    float e = eta[t];
    kgam_l[t] = -LOG2E * e * e;                          // exp(-g*d) = exp2(kgam*d)
    alph_l[t] = 1.f / (1.f + __expf(-xi[t]));
  }
  __syncthreads();                                       // B2

  // ---- si + beta sumsq partials (parallel phase) ----
  {
    const int p4 = t >> 2, q4 = t & 3;                   // beta partials -> red_l
    const float* br = beta + p4 * NC + q4 * 25;
    float s = 0.f;
    #pragma unroll 5
    for (int j = 0; j < 25; ++j) { float b = br[j]; s = fmaf(b, b, s); }
    red_l[q4 * 64 + p4] = s;
  }
  {
    const int row = t >> 4, p = (t & 15) * 4;
    float4 dt = *(const float4*)&d_l[row * 68 + p];
    const float xs = xsql[row];
    float si0 = alph_l[p+0] * exp2f(kgam_l[p+0] * (xs + wsql[p+0] - 2.f * dt.x));
    float si1 = alph_l[p+1] * exp2f(kgam_l[p+1] * (xs + wsql[p+1] - 2.f * dt.y));
    float si2 = alph_l[p+2] * exp2f(kgam_l[p+2] * (xs + wsql[p+2] - 2.f * dt.z));
    float si3 = alph_l[p+3] * exp2f(kgam_l[p+3] * (xs + wsql[p+3] - 2.f * dt.w));
    float mx = fmaxf(fmaxf(si0, si1), fmaxf(si2, si3));
    #pragma unroll
    for (int msk = 1; msk < 16; msk <<= 1) mx = fmaxf(mx, __shfl_xor(mx, msk, 64));
    const float rinv = 1.f / (mx + EPSF);
    float4 sv = make_float4(si0 * rinv, si1 * rinv, si2 * rinv, si3 * rinv);
    *(float4*)&si_l[row * 64 + p] = sv;
  }
  __syncthreads();                                       // B3
  if (t < 64) binv_l[t] = 1.f / (((red_l[t] + red_l[64 + t]) + red_l[128 + t]) + red_l[192 + t]);
  __syncthreads();                                       // B4
  {                                                      // u fill (over dead w staging)
    const int p4 = t >> 2, q4 = t & 3;
    const float bi = binv_l[p4];
    #pragma unroll
    for (int i = 0; i < 8; ++i) {
      const int q = q4 + 4 * i;                          // col quad 0..31
      float4 uv = make_float4(0.f, 0.f, 0.f, 0.f);
      if (q < 25) {
        const float* br = beta + p4 * NC + q * 4;
        float b0 = br[0], b1 = br[1], b2 = br[2], b3 = br[3];
        uv = make_float4(b0*b0*bi, b1*b1*bi, b2*b2*bi, b3*b3*bi);
      }
      *(float4*)&u_l[p4 * 128 + q * 4] = uv;
    }
  }
  __syncthreads();                                       // B5

  // ---- Dempster scan: 2 passes of 8 rows, half-wave (32 lanes) per row ----
  const int lane = t & 31;
  const bool isom = (lane == 25);                        // class 100 at lane 25 slot 0
  #pragma unroll
  for (int pass = 0; pass < 2; ++pass) {
    const int row = pass * 8 + (t >> 5);
    const float* sirow = &si_l[row * 64];
    float4 u0 = *(const float4*)&u_l[lane * 4];
    float sp  = sirow[0];
    float m0 = sp * u0.x, m1 = sp * u0.y, m2 = sp * u0.z, m3 = sp * u0.w;
    float om1 = 1.f - sp;
    if (isom) m0 = om1;

    for (int p = 1; p < NP; ++p) {
      sp = sirow[p];
      float4 u = *(const float4*)&u_l[p * 128 + lane * 4];
      float om2 = 1.f - sp;
      float nom = -(om1 * om2);
      float t20 = fmaf(sp, u.x, om2);
      t20 = isom ? (om2 + om2) : t20;                    // omega slot: m2+om2 = 2*om2
      float t21 = fmaf(sp, u.y, om2);
      float t22 = fmaf(sp, u.z, om2);
      float t23 = fmaf(sp, u.w, om2);
      m0 = fmaf(m0 + om1, t20, nom);
      m1 = fmaf(m1 + om1, t21, nom);
      m2 = fmaf(m2 + om1, t22, nom);
      m3 = fmaf(m3 + om1, t23, nom);
      om1 = fmaf(nom, -2.f, -nom);                       // 3*om1*om2
      if (isom) m0 = om1;
      if ((p & 3) == 0) {                                // pure-scale renorm
        float ss = (m0 + m1) + (m2 + m3);
        #pragma unroll
        for (int msk = 1; msk < 32; msk <<= 1) ss += __shfl_xor(ss, msk, 64);
        float rn = __builtin_amdgcn_rcpf(ss);
        m0 *= rn; m1 *= rn; m2 *= rn; m3 *= rn; om1 *= rn;
      }
    }

    float ss = (m0 + m1) + (m2 + m3);
    #pragma unroll
    for (int msk = 1; msk < 32; msk <<= 1) ss += __shfl_xor(ss, msk, 64);
    float rn = 1.f / ss;                                 // final normalize (no EPS)
    m0 *= rn; m1 *= rn; m2 *= rn; m3 *= rn;

    float* orow = &out[(size_t)(R0 + row) * 101];
    if (lane < 25) {
      orow[lane*4+0] = m0; orow[lane*4+1] = m1;
      orow[lane*4+2] = m2; orow[lane*4+3] = m3;
    } else if (lane == 25) {
      orow[100] = m0;
    }
  }
}

extern "C" void kernel_launch(void* const* d_in, const int* in_sizes, int n_in,
                              void* d_out, int out_size, void* d_ws, size_t ws_size,
                              hipStream_t stream)
{
  const float* x    = (const float*)d_in[0];
  const float* w    = (const float*)d_in[1];
  const float* xi   = (const float*)d_in[2];
  const float* eta  = (const float*)d_in[3];
  const float* beta = (const float*)d_in[4];
  (void)d_ws; (void)ws_size;
  hipLaunchKernelGGL(ds_fused2, dim3(NB / NR), dim3(256), 0, stream,
                     x, w, xi, eta, beta, (float*)d_out);
}

// Round 7
// 85.174 us; speedup vs baseline: 1.4082x; 1.1231x over previous
//
#include <hip/hip_runtime.h>
#include <math.h>

#define NB 8192
#define NF 512
#define NP 64
#define NC 100
#define NR 16
#define EPSF 1e-4f
#define LOG2E  1.44269504088896340736f
#define LOG2_3 1.58496250072115618145f

using short8  = __attribute__((ext_vector_type(8))) short;
using floatx4 = __attribute__((ext_vector_type(4))) float;

// pack float4 -> 4 bf16 (truncation). out is omega-dominated; si distortion
// from truncated-bf16 d shifts out by <~3e-4 absolute (threshold 2e-2).
__device__ __forceinline__ uint2 pkbf(float4 v) {
  uint2 r;
  r.x = (__float_as_uint(v.y) & 0xffff0000u) | (__float_as_uint(v.x) >> 16);
  r.y = (__float_as_uint(v.w) & 0xffff0000u) | (__float_as_uint(v.z) >> 16);
  return r;
}

// ---- LDS layout (unions; bytes) ----
// GEMM phase:  xh [0,2304) wh [2304,11520)   (dead after K-loop)
// scan phase:  u_l [0,32768) pk4 [32768,40960)
#define OFF_XH    0
#define OFF_WH    2304
#define OFF_U     0
#define OFF_PK4   32768
#define OFF_SI    40960
#define OFF_REDB  45056
#define OFF_RMAX  46080
#define OFF_UMAX  46336
#define OFF_XSQL  46592
#define OFF_WSQL  46656
#define OFF_KGAM  46912
#define OFF_ALPH  47168
#define OFF_BINV  47424
#define OFF_OMF   47680
#define SMEM_SZ   47712

// One fused kernel, 512 blocks x 256 threads, 16 rows/block, ~46.6 KB LDS
// -> 3 blocks/CU. GEMM: pure-bf16 MFMA 16x16x32, BK=64, conflict-free
// staging (16 consecutive lanes per row). Scan: suffix-product reformulation
//   v' = v1*v2 + 2*om1*om2, om' = 3*om1*om2  (degree-1/step => per-step
//   scaling cancels in final normalize):
//   v_fin[c] = prod_p v~_p[c] + 2 * sum_k 3^(k-1) Om~_k * T_k[c],
//   T_k = prod_{j>k} v~_j,  om_fin = 3^63 * Om~_63,  m = v_fin - om_fin.
// 3 VALU/class/step, no shuffles/renorms in the hot loop.
// All reductions fixed-order/butterfly => bitwise deterministic (graph tripwire).
__global__ __launch_bounds__(256, 3)
void ds_one(const float* __restrict__ x, const float* __restrict__ w,
            const float* __restrict__ xi, const float* __restrict__ eta,
            const float* __restrict__ beta, float* __restrict__ out)
{
  __shared__ __align__(16) char smem[SMEM_SZ];
  short*  xh    = (short*)(smem + OFF_XH);
  short*  wh    = (short*)(smem + OFF_WH);
  float*  u_l   = (float*)(smem + OFF_U);
  float4* pk4   = (float4*)(smem + OFF_PK4);
  float*  si_l  = (float*)(smem + OFF_SI);
  float*  redb  = (float*)(smem + OFF_REDB);
  float*  rmax  = (float*)(smem + OFF_RMAX);
  float*  umax  = (float*)(smem + OFF_UMAX);
  float*  xsql  = (float*)(smem + OFF_XSQL);
  float*  wsql  = (float*)(smem + OFF_WSQL);
  float*  kgaml = (float*)(smem + OFF_KGAM);
  float*  alphl = (float*)(smem + OFF_ALPH);
  float*  binv  = (float*)(smem + OFF_BINV);
  float*  omf   = (float*)(smem + OFF_OMF);

  const int t    = threadIdx.x;
  const int R0   = blockIdx.x * NR;
  const int wv   = t >> 6;               // wave -> p-tile [16wv, 16wv+16)
  const int ml   = t & 15;               // MFMA m/n lane
  const int qd   = (t & 63) >> 4;        // MFMA quad
  const int xrow = t >> 4, xq = t & 15;  // staging roles
  const int wl   = t & 63;

  // ---- GEMM: D = x . w^T, bf16 MFMA, BK=64, 8 chunks ----
  float xsq_acc = 0.f;
  float wacc[4] = {0.f, 0.f, 0.f, 0.f};
  floatx4 acc = {0.f, 0.f, 0.f, 0.f};

  for (int ch = 0; ch < 8; ++ch) {
    const int kb = ch * 64;
    __syncthreads();                      // prev chunk's frags consumed
    {
      float4 v = *(const float4*)&x[(size_t)(R0 + xrow) * NF + kb + xq * 4];
      xsq_acc += v.x*v.x + v.y*v.y + v.z*v.z + v.w*v.w;
      *(uint2*)&xh[xrow * 72 + xq * 4] = pkbf(v);       // 16 lanes/row: conflict-free
    }
    #pragma unroll
    for (int g = 0; g < 4; ++g) {
      const int row = wv * 16 + g * 4 + (wl >> 4);
      float4 v = *(const float4*)&w[(size_t)row * NF + kb + xq * 4];
      wacc[g] += v.x*v.x + v.y*v.y + v.z*v.z + v.w*v.w;
      *(uint2*)&wh[row * 72 + xq * 4] = pkbf(v);
    }
    __syncthreads();
    #pragma unroll
    for (int ks = 0; ks < 2; ++ks) {
      short8 a = *(const short8*)&xh[ml * 72 + ks * 32 + qd * 8];
      short8 b = *(const short8*)&wh[(wv * 16 + ml) * 72 + ks * 32 + qd * 8];
      acc = __builtin_amdgcn_mfma_f32_16x16x32_bf16(a, b, acc, 0, 0, 0);
    }
  }

  // ---- P1: beta partials, xsq/wsq butterfly reduces, kgam/alpha ----
  {
    const int p4 = t >> 2, q4 = t & 3;
    const float* br = beta + p4 * NC + q4 * 25;
    float s = 0.f;
    #pragma unroll 5
    for (int j = 0; j < 25; ++j) { float b = br[j]; s = fmaf(b, b, s); }
    redb[q4 * 64 + p4] = s;
  }
  {
    float s = xsq_acc;
    s += __shfl_xor(s, 1, 64); s += __shfl_xor(s, 2, 64);
    s += __shfl_xor(s, 4, 64); s += __shfl_xor(s, 8, 64);
    if (xq == 0) xsql[xrow] = s;
  }
  #pragma unroll
  for (int g = 0; g < 4; ++g) {
    float s = wacc[g];
    s += __shfl_xor(s, 1, 64); s += __shfl_xor(s, 2, 64);
    s += __shfl_xor(s, 4, 64); s += __shfl_xor(s, 8, 64);
    if (xq == 0) wsql[wv * 16 + g * 4 + (wl >> 4)] = s;
  }
  if (t < 64) {
    float e = eta[t];
    kgaml[t] = -LOG2E * e * e;            // exp(-g*d) = exp2(kgam*d)
    alphl[t] = 1.f / (1.f + __expf(-xi[t]));
  }
  __syncthreads();                        // B1

  // ---- P2: binv; si in MFMA-C layout + per-row wave-max ----
  if (t < 64) binv[t] = 1.f / (((redb[t] + redb[64 + t]) + redb[128 + t]) + redb[192 + t]);
  const int pcol = wv * 16 + ml;
  float si4[4];
  {
    const float wq = wsql[pcol], kg = kgaml[pcol], al = alphl[pcol];
    #pragma unroll
    for (int i = 0; i < 4; ++i) {
      float d = xsql[qd * 4 + i] + wq - 2.f * acc[i];
      si4[i] = al * exp2f(kg * d);
    }
    #pragma unroll
    for (int i = 0; i < 4; ++i) {
      float m = si4[i];
      m = fmaxf(m, __shfl_xor(m, 1, 64)); m = fmaxf(m, __shfl_xor(m, 2, 64));
      m = fmaxf(m, __shfl_xor(m, 4, 64)); m = fmaxf(m, __shfl_xor(m, 8, 64));
      if (ml == 0) rmax[(qd * 4 + i) * 4 + wv] = m;
    }
  }
  __syncthreads();                        // B2

  // ---- P3: u fill (over dead staging) + umax; si finalize -> si_l ----
  {
    const int p4 = t >> 2, q4 = t & 3;
    const float bi = binv[p4];
    float um = 0.f;
    #pragma unroll
    for (int i2 = 0; i2 < 8; ++i2) {
      const int q = q4 + 4 * i2;          // col quad 0..31 (NC=100 = quads 0..24)
      float4 uv = make_float4(0.f, 0.f, 0.f, 0.f);
      if (q < 25) {
        const float* br = beta + p4 * NC + q * 4;
        uv.x = br[0]*br[0]*bi; uv.y = br[1]*br[1]*bi;
        uv.z = br[2]*br[2]*bi; uv.w = br[3]*br[3]*bi;
      }
      um = fmaxf(um, fmaxf(fmaxf(uv.x, uv.y), fmaxf(uv.z, uv.w)));
      *(float4*)&u_l[p4 * 128 + q * 4] = uv;
    }
    um = fmaxf(um, __shfl_xor(um, 1, 64));
    um = fmaxf(um, __shfl_xor(um, 2, 64));
    if (q4 == 0) umax[p4] = um;
  }
  #pragma unroll
  for (int i = 0; i < 4; ++i) {
    const int row = qd * 4 + i;
    float m = fmaxf(fmaxf(rmax[row * 4 + 0], rmax[row * 4 + 1]),
                    fmaxf(rmax[row * 4 + 2], rmax[row * 4 + 3]));
    si_l[row * 64 + pcol] = si4[i] * (1.f / (m + EPSF));
  }
  __syncthreads();                        // B3

  // ---- scan: 2 passes of 8 rows; half-wave (32 lanes) per row ----
  const int lane = t & 31;
  const int row8 = t >> 5;
  #pragma unroll 1
  for (int pass = 0; pass < 2; ++pass) {
    const int srow = pass * 8 + row8;
    {   // precompute scaled (s~, om~, w~) per p; Kogge-Stone prefix products
      float sp0 = si_l[srow * 64 + lane];
      float sp1 = si_l[srow * 64 + 32 + lane];
      float um0 = umax[lane], um1 = umax[32 + lane];
      float om0 = 1.f - sp0, om1 = 1.f - sp1;
      float c0 = 1.f / fmaf(sp0, um0, om0);   // scale: max_c(v~) = 1 -> T <= 1
      float c1 = 1.f / fmaf(sp1, um1, om1);
      float st0 = sp0 * c0, ot0 = om0 * c0;
      float st1 = sp1 * c1, ot1 = om1 * c1;
      float pA = ot0, pB = ot1;
      #pragma unroll
      for (int d2 = 1; d2 < 32; d2 <<= 1) {
        float uA = __shfl_up(pA, d2, 32);
        float uB = __shfl_up(pB, d2, 32);
        if (lane >= d2) { pA *= uA; pB *= uB; }
      }
      float totA = __shfl(pA, 31, 32);
      float w0 = (lane == 0) ? 0.f : exp2f((float)(lane - 1) * LOG2_3) * pA;
      float w1 = exp2f((float)(lane + 31) * LOG2_3) * (totA * pB);
      pk4[row8 * 64 + lane]      = make_float4(st0, ot0, w0, 0.f);
      pk4[row8 * 64 + 32 + lane] = make_float4(st1, ot1, w1, 0.f);
      if (lane == 31) omf[row8] = 3.f * exp2f(62.f * LOG2_3) * (totA * pB);
    }
    __syncthreads();                      // B4: pk4/omf ready
    float4 T = make_float4(1.f, 1.f, 1.f, 1.f);
    float4 S = make_float4(0.f, 0.f, 0.f, 0.f);
    for (int p = 63; p >= 0; --p) {       // S += w_k*T BEFORE T *= v_k
      float4 f  = pk4[row8 * 64 + p];     // (s~, om~, w~) broadcast
      float4 uv = *(const float4*)&u_l[p * 128 + lane * 4];
      S.x = fmaf(f.z, T.x, S.x); S.y = fmaf(f.z, T.y, S.y);
      S.z = fmaf(f.z, T.z, S.z); S.w = fmaf(f.z, T.w, S.w);
      T.x *= fmaf(f.x, uv.x, f.y);
      T.y *= fmaf(f.x, uv.y, f.y);
      T.z *= fmaf(f.x, uv.z, f.y);
      T.w *= fmaf(f.x, uv.w, f.y);
    }
    float om = omf[row8];
    float m0 = fmaf(2.f, S.x, T.x) - om;
    float m1 = fmaf(2.f, S.y, T.y) - om;
    float m2 = fmaf(2.f, S.z, T.z) - om;
    float m3 = fmaf(2.f, S.w, T.w) - om;
    if (lane >= 25) { m0 = 0.f; m1 = 0.f; m2 = 0.f; m3 = 0.f; }
    float ss = (m0 + m1) + (m2 + m3);
    #pragma unroll
    for (int msk = 1; msk < 32; msk <<= 1) ss += __shfl_xor(ss, msk, 32);
    float rn = 1.f / (ss + om);
    float* orow = &out[(size_t)(R0 + srow) * 101];
    if (lane < 25) {
      orow[lane * 4 + 0] = m0 * rn; orow[lane * 4 + 1] = m1 * rn;
      orow[lane * 4 + 2] = m2 * rn; orow[lane * 4 + 3] = m3 * rn;
    } else if (lane == 25) {
      orow[100] = om * rn;
    }
    __syncthreads();                      // B5: pk4 reusable next pass
  }
}

extern "C" void kernel_launch(void* const* d_in, const int* in_sizes, int n_in,
                              void* d_out, int out_size, void* d_ws, size_t ws_size,
                              hipStream_t stream)
{
  const float* x    = (const float*)d_in[0];
  const float* w    = (const float*)d_in[1];
  const float* xi   = (const float*)d_in[2];
  const float* eta  = (const float*)d_in[3];
  const float* beta = (const float*)d_in[4];
  (void)d_ws; (void)ws_size;
  hipLaunchKernelGGL(ds_one, dim3(NB / NR), dim3(256), 0, stream,
                     x, w, xi, eta, beta, (float*)d_out);
}